// Round 6
// baseline (2928.295 us; speedup 1.0000x reference)
//
#include <hip/hip_runtime.h>

#define ALPHA 0.3f
#define BNEPS 1e-3f

typedef __attribute__((ext_vector_type(8))) short bf16x8;
typedef __attribute__((ext_vector_type(4))) float f32x4;

__device__ __forceinline__ short f2bf(float x){
    unsigned u = __float_as_uint(x);
    unsigned r = (u + 0x7FFFu + ((u >> 16) & 1u)) >> 16;   // RNE
    return (short)r;
}
__device__ __forceinline__ float bf2f(short s){
    return __uint_as_float(((unsigned)(unsigned short)s) << 16);
}

// ---------------- routing: counting sort of samples by class ----------------
__global__ void sort_k(const int* __restrict__ labels, int* __restrict__ order){
    __shared__ int cnt[10], offs[10];
    int tid = threadIdx.x;
    if (tid < 10) cnt[tid] = 0;
    __syncthreads();
    int lab = labels[tid];
    atomicAdd(&cnt[lab], 1);
    __syncthreads();
    if (tid == 0){
        int s = 0;
        for (int c = 0; c < 10; c++){ offs[c] = s; s += cnt[c]; }
    }
    __syncthreads();
    int pos = atomicAdd(&offs[lab], 1);
    order[pos] = tid;
}

// ---------------- weight prep: fp32 -> bf16 hi/lo, B-fragment layout ----------------
// W1T: [ct=c*25+tap][chunk=ci/8 (40)][co (256)][ci%8]   ci in [0,320), >=306 zero
// W2T: [ct][chunk=ci/8 (32)][co (128)][ci%8]
#define N1 20480000   // 10*25*40*256*8
#define N2 8192000    // 10*25*32*128*8
__global__ void prep_k(const float* __restrict__ K1, const float* __restrict__ K2,
                       short* __restrict__ w1h, short* __restrict__ w1l,
                       short* __restrict__ w2h, short* __restrict__ w2l){
    int i = blockIdx.x * 256 + threadIdx.x;
    if (i < N1){
        int j  = i & 7;
        int co = (i >> 3) & 255;
        int ch = (i >> 11) % 40;
        int ct = (i >> 11) / 40;
        int ci = ch*8 + j;
        float w = (ci < 306) ? K1[((size_t)ct*306 + ci)*256 + co] : 0.f;
        short h = f2bf(w); short l = f2bf(w - bf2f(h));
        w1h[i] = h; w1l[i] = l;
    } else {
        int k  = i - N1;
        int j  = k & 7;
        int co = (k >> 3) & 127;
        int ch = (k >> 10) & 31;
        int ct = (k >> 10) >> 5;
        int ci = ch*8 + j;
        float w = K2[((size_t)ct*256 + ci)*128 + co];
        short h = f2bf(w); short l = f2bf(w - bf2f(h));
        w2h[k] = h; w2l[k] = l;
    }
}

// ---------------- dense 150->12544 + BN1 + LReLU -> xcat hi/lo bf16 in ws ----------------
// xg[b][q 49][ci 320]; cols 256..305 = label emb; 306..319 = 0
__global__ __launch_bounds__(256, 2)
void dense_k(const float* __restrict__ noise, const int* __restrict__ labels,
             const float* __restrict__ emb,   const float* __restrict__ Wd,
             const float* __restrict__ g1, const float* __restrict__ b1,
             const float* __restrict__ m1, const float* __restrict__ v1,
             short* __restrict__ xgH, short* __restrict__ xgL){
    __shared__ float xin[2][152];
    const int tid = threadIdx.x;
    const int b0 = blockIdx.x * 2;
    for (int i = tid; i < 300; i += 256){
        int s = i / 150, k = i % 150;
        int b = b0 + s;
        xin[s][k] = (k < 100) ? noise[b*100 + k] : emb[labels[b]*50 + (k-100)];
    }
    __syncthreads();
    const int co = tid;
    float a0[49], a1[49];
    #pragma unroll
    for (int q = 0; q < 49; q++){ a0[q] = 0.f; a1[q] = 0.f; }
    #pragma unroll 1
    for (int k = 0; k < 150; k++){
        float x0 = xin[0][k], x1 = xin[1][k];
        const float* wr = Wd + k*12544 + co;
        #pragma unroll
        for (int q = 0; q < 49; q++){
            float w = wr[q*256];
            a0[q] += x0 * w;
            a1[q] += x1 * w;
        }
    }
    #pragma unroll 1
    for (int q = 0; q < 49; q++){
        int j = q*256 + co;
        float sc = g1[j] * rsqrtf(v1[j] + BNEPS);
        float mm = m1[j], bb = b1[j];
        float y0 = (a0[q]-mm)*sc + bb;  y0 = (y0 >= 0.f) ? y0 : ALPHA*y0;
        float y1 = (a1[q]-mm)*sc + bb;  y1 = (y1 >= 0.f) ? y1 : ALPHA*y1;
        short h0 = f2bf(y0), l0 = f2bf(y0 - bf2f(h0));
        short h1 = f2bf(y1), l1 = f2bf(y1 - bf2f(h1));
        size_t o0 = ((size_t)b0*49 + q)*320 + co;
        size_t o1 = ((size_t)(b0+1)*49 + q)*320 + co;
        xgH[o0] = h0; xgL[o0] = l0;
        xgH[o1] = h1; xgL[o1] = l1;
    }
    if (co < 50){
        for (int s = 0; s < 2; s++){
            float v = xin[s][100 + co];
            short h = f2bf(v), l = f2bf(v - bf2f(h));
            for (int q = 0; q < 49; q++){
                size_t o = ((size_t)(b0+s)*49 + q)*320 + 256 + co;
                xgH[o] = h; xgL[o] = l;
            }
        }
    }
    if (co < 14){
        for (int s = 0; s < 2; s++)
            for (int q = 0; q < 49; q++){
                size_t o = ((size_t)(b0+s)*49 + q)*320 + 306 + co;
                xgH[o] = 0; xgL[o] = 0;
            }
    }
}

// ---------------- main: conv1 + conv2 (MFMA) + conv3 (VALU), 2 samples/block ----------------
__global__ __launch_bounds__(512, 2)
void main_k(const int* __restrict__ labels, const int* __restrict__ order,
            const short* __restrict__ xgH, const short* __restrict__ xgL,
            const short* __restrict__ w1h, const short* __restrict__ w1l,
            const short* __restrict__ w2h, const short* __restrict__ w2l,
            const float* __restrict__ G1, const float* __restrict__ B1,
            const float* __restrict__ M1, const float* __restrict__ V1,
            const float* __restrict__ G2, const float* __restrict__ B2,
            const float* __restrict__ M2, const float* __restrict__ V2,
            const float* __restrict__ K3, float* __restrict__ out){
    // smem overlay:
    //  phase conv1-in : xa1[s][h] = smem + (s*2+h)*16400, rows 50 x stride 328 (shorts)
    //  phase conv2-in : xa2[s][h] = smem + (s*2+h)*13200, rows 50 x stride 264
    //  phase conv3    : h2f (196*132 f32) + wk3 (3200 f32) over same bytes
    __shared__ __align__(16) short smem[65600];          // 131,200 B
    __shared__ int binfo[4];                             // b0,b1,c0,c1
    const int tid = threadIdx.x;
    const int idx = ((blockIdx.x & 7) << 5) | (blockIdx.x >> 3);   // XCD swizzle, 256 blocks
    if (tid < 2){
        int b = order[2*idx + tid];
        binfo[tid] = b;
        binfo[2 + tid] = labels[b];
    }
    {   // zero LDS (padding rows/cols rely on this)
        uint4 z; z.x = z.y = z.z = z.w = 0;
        uint4* p = (uint4*)smem;
        for (int i = tid; i < 8200; i += 512) p[i] = z;
    }
    __syncthreads();
    // copy xcat rows (s,h,q): 196 rows x 40 uint4
    for (int i = tid; i < 7840; i += 512){
        int t = i % 40, w = i / 40;
        int q = w % 49, sh = w / 49;
        int s = sh >> 1, h = sh & 1;
        const short* src = (h ? xgL : xgH) + ((size_t)binfo[s]*49 + q)*320;
        *(uint4*)&smem[sh*16400 + q*328 + t*8] = *(const uint4*)&src[t*8];
    }
    __syncthreads();

    const int lane = tid & 63, wid = tid >> 6;
    const int m15 = lane & 15, quad = lane >> 4;

    // ================= conv1: 7x7x306 -> 7x7x256 (s=1, pads 2,2) =================
    {
        const int s = wid & 1, nq = wid >> 1;          // wave = (sample, n-quarter)
        const int c = binfo[2 + s];
        const short* xh = smem + (s*2 + 0)*16400;
        const short* xl = smem + (s*2 + 1)*16400;
        f32x4 acc[4][4];
        #pragma unroll
        for (int a = 0; a < 4; a++)
            #pragma unroll
            for (int b = 0; b < 4; b++){ acc[a][b][0]=0.f; acc[a][b][1]=0.f; acc[a][b][2]=0.f; acc[a][b][3]=0.f; }

        #pragma unroll 1
        for (int tap = 0; tap < 25; tap++){
            int ky = tap / 5, kx = tap % 5;
            int aoff[4];
            #pragma unroll
            for (int mi = 0; mi < 4; mi++){
                int p = mi*16 + m15;
                int py = p / 7, px = p % 7;
                int iy = py + ky - 2, ix = px + kx - 2;
                bool ok = (p < 49) & (iy >= 0) & (iy < 7) & (ix >= 0) & (ix < 7);
                int q = ok ? iy*7 + ix : 49;           // row 49 = zeros
                aoff[mi] = q*328 + quad*8;
            }
            const short *bh[4], *bl[4];
            size_t tapbase = ((size_t)(c*25 + tap))*40*256*8;
            #pragma unroll
            for (int ni = 0; ni < 4; ni++){
                int co = nq*64 + ni*16 + m15;
                size_t off = tapbase + ((size_t)quad*256 + co)*8;
                bh[ni] = w1h + off; bl[ni] = w1l + off;
            }
            #pragma unroll
            for (int ks = 0; ks < 10; ks++){
                bf16x8 Ah[4], Al[4], Bh[4], Bl[4];
                #pragma unroll
                for (int mi = 0; mi < 4; mi++){
                    Ah[mi] = *(const bf16x8*)&xh[aoff[mi] + ks*32];
                    Al[mi] = *(const bf16x8*)&xl[aoff[mi] + ks*32];
                }
                #pragma unroll
                for (int ni = 0; ni < 4; ni++){
                    Bh[ni] = *(const bf16x8*)&bh[ni][ks*8192];
                    Bl[ni] = *(const bf16x8*)&bl[ni][ks*8192];
                }
                #pragma unroll
                for (int mi = 0; mi < 4; mi++)
                    #pragma unroll
                    for (int ni = 0; ni < 4; ni++){
                        acc[mi][ni] = __builtin_amdgcn_mfma_f32_16x16x32_bf16(Ah[mi], Bh[ni], acc[mi][ni], 0, 0, 0);
                        acc[mi][ni] = __builtin_amdgcn_mfma_f32_16x16x32_bf16(Ah[mi], Bl[ni], acc[mi][ni], 0, 0, 0);
                        acc[mi][ni] = __builtin_amdgcn_mfma_f32_16x16x32_bf16(Al[mi], Bh[ni], acc[mi][ni], 0, 0, 0);
                    }
            }
        }
        __syncthreads();   // all conv1 LDS reads complete
        // epilogue: BN + LReLU -> xa2 (hi/lo), + zero row 49
        float sc[4], mm[4], bb[4];
        #pragma unroll
        for (int ni = 0; ni < 4; ni++){
            int co = nq*64 + ni*16 + m15;
            sc[ni] = G1[c*256 + co] * rsqrtf(V1[c*256 + co] + BNEPS);
            mm[ni] = M1[c*256 + co];
            bb[ni] = B1[c*256 + co];
        }
        short* yh = smem + (s*2 + 0)*13200;
        short* yl = smem + (s*2 + 1)*13200;
        yh[49*264 + nq*64 + lane] = 0;
        yl[49*264 + nq*64 + lane] = 0;
        #pragma unroll
        for (int mi = 0; mi < 4; mi++)
            #pragma unroll
            for (int r = 0; r < 4; r++){
                int p = mi*16 + quad*4 + r;
                if (p < 49){
                    #pragma unroll
                    for (int ni = 0; ni < 4; ni++){
                        float y = (acc[mi][ni][r] - mm[ni])*sc[ni] + bb[ni];
                        y = (y >= 0.f) ? y : ALPHA*y;
                        short h = f2bf(y), l = f2bf(y - bf2f(h));
                        int o = p*264 + nq*64 + ni*16 + m15;
                        yh[o] = h; yl[o] = l;
                    }
                }
            }
    }
    __syncthreads();

    // ================= conv2: 7x7x256 -> 14x14x128 (s=2, pads 3,2), parity split =================
    {
        const int s = wid & 1, par = wid >> 1;         // wave = (sample, parity)
        const int pi = par >> 1, pj = par & 1;
        const int c = binfo[2 + s];
        const short* xh = smem + (s*2 + 0)*13200;
        const short* xl = smem + (s*2 + 1)*13200;
        f32x4 acc[2][4][4];                            // [nhalf][mi][ni]
        #pragma unroll
        for (int a = 0; a < 2; a++)
            #pragma unroll
            for (int b = 0; b < 4; b++)
                #pragma unroll
                for (int d = 0; d < 4; d++){ acc[a][b][d][0]=0.f; acc[a][b][d][1]=0.f; acc[a][b][d][2]=0.f; acc[a][b][d][3]=0.f; }

        const int nky = pi ? 3 : 2, kyb = pi ? 0 : 1;
        const int nkx = pj ? 3 : 2, kxb = pj ? 0 : 1;
        #pragma unroll 1
        for (int nh = 0; nh < 2; nh++){
            #pragma unroll 1
            for (int ty = 0; ty < nky; ty++){
                int ky = kyb + 2*ty;
                int dy = (pi + ky - 3) / 2;            // always even numerator
                #pragma unroll 1
                for (int tx = 0; tx < nkx; tx++){
                    int kx = kxb + 2*tx;
                    int dx = (pj + kx - 3) / 2;
                    int tap = ky*5 + kx;
                    int aoff[4];
                    #pragma unroll
                    for (int mi = 0; mi < 4; mi++){
                        int p = mi*16 + m15;
                        int oy = p / 7, ox = p % 7;
                        int u = oy + dy, v = ox + dx;
                        bool ok = (p < 49) & (u >= 0) & (u < 7) & (v >= 0) & (v < 7);
                        int q = ok ? u*7 + v : 49;
                        aoff[mi] = q*264 + quad*8;
                    }
                    const short *bh[4], *bl[4];
                    size_t tapbase = ((size_t)(c*25 + tap))*32*128*8;
                    #pragma unroll
                    for (int ni = 0; ni < 4; ni++){
                        int co = nh*64 + ni*16 + m15;
                        size_t off = tapbase + ((size_t)quad*128 + co)*8;
                        bh[ni] = w2h + off; bl[ni] = w2l + off;
                    }
                    #pragma unroll
                    for (int ks = 0; ks < 8; ks++){
                        bf16x8 Ah[4], Al[4];
                        #pragma unroll
                        for (int mi = 0; mi < 4; mi++){
                            Ah[mi] = *(const bf16x8*)&xh[aoff[mi] + ks*32];
                            Al[mi] = *(const bf16x8*)&xl[aoff[mi] + ks*32];
                        }
                        #pragma unroll
                        for (int ni = 0; ni < 4; ni++){
                            bf16x8 Bh = *(const bf16x8*)&bh[ni][ks*4096];
                            bf16x8 Bl = *(const bf16x8*)&bl[ni][ks*4096];
                            #pragma unroll
                            for (int mi = 0; mi < 4; mi++){
                                acc[nh][mi][ni] = __builtin_amdgcn_mfma_f32_16x16x32_bf16(Ah[mi], Bh, acc[nh][mi][ni], 0, 0, 0);
                                acc[nh][mi][ni] = __builtin_amdgcn_mfma_f32_16x16x32_bf16(Ah[mi], Bl, acc[nh][mi][ni], 0, 0, 0);
                                acc[nh][mi][ni] = __builtin_amdgcn_mfma_f32_16x16x32_bf16(Al[mi], Bh, acc[nh][mi][ni], 0, 0, 0);
                            }
                        }
                    }
                }
            }
        }
        __syncthreads();   // all conv2 LDS reads complete; smem free
        // BN params
        float sc[2][4], mm[2][4], bb[2][4];
        #pragma unroll
        for (int nh = 0; nh < 2; nh++)
            #pragma unroll
            for (int ni = 0; ni < 4; ni++){
                int co = nh*64 + ni*16 + m15;
                sc[nh][ni] = G2[c*128 + co] * rsqrtf(V2[c*128 + co] + BNEPS);
                mm[nh][ni] = M2[c*128 + co];
                bb[nh][ni] = B2[c*128 + co];
            }
        float* h2f = (float*)smem;          // 196*132
        float* wk3 = (float*)smem + 25872;  // 3200
        // per-sample conv3 phases
        #pragma unroll 1
        for (int sp = 0; sp < 2; sp++){
            if (s == sp){
                #pragma unroll
                for (int nh = 0; nh < 2; nh++)
                    #pragma unroll
                    for (int mi = 0; mi < 4; mi++)
                        #pragma unroll
                        for (int r = 0; r < 4; r++){
                            int p = mi*16 + quad*4 + r;
                            if (p < 49){
                                int oy = p / 7, ox = p % 7;
                                int q2 = (2*oy + pi)*14 + (2*ox + pj);
                                #pragma unroll
                                for (int ni = 0; ni < 4; ni++){
                                    float y = (acc[nh][mi][ni][r] - mm[nh][ni])*sc[nh][ni] + bb[nh][ni];
                                    y = (y >= 0.f) ? y : ALPHA*y;
                                    h2f[q2*132 + nh*64 + ni*16 + m15] = y;
                                }
                            }
                        }
            }
            int cs = binfo[2 + sp];
            for (int i = tid; i < 3200; i += 512) wk3[i] = K3[cs*3200 + i];
            __syncthreads();
            // conv3: 14x14x128 -> 28x28x1, s=2, pads (3,2), tanh
            #pragma unroll 1
            for (int rep = 0; rep < 2; rep++){
                int p3 = tid + rep*512;
                if (p3 < 784){
                    int oi = p3 / 28, oj = p3 % 28;
                    float a3 = 0.f;
                    #pragma unroll
                    for (int ky = 0; ky < 5; ky++){
                        int t = oi + ky - 3;
                        if (t < 0 || (t & 1) || t >= 28) continue;
                        int u = t >> 1;
                        #pragma unroll
                        for (int kx = 0; kx < 5; kx++){
                            int ss2 = oj + kx - 3;
                            if (ss2 < 0 || (ss2 & 1) || ss2 >= 28) continue;
                            int v = ss2 >> 1;
                            const float* xr = &h2f[(u*14 + v)*132];
                            const float* w = &wk3[(ky*5 + kx)*128];
                            #pragma unroll
                            for (int cc = 0; cc < 32; cc++){
                                float4 xv = *(const float4*)&xr[4*cc];
                                float4 wv = *(const float4*)&w[4*cc];
                                a3 += xv.x*wv.x + xv.y*wv.y + xv.z*wv.z + xv.w*wv.w;
                            }
                        }
                    }
                    out[binfo[sp]*784 + p3] = tanhf(a3);
                }
            }
            __syncthreads();   // before next sp overwrites h2f
        }
    }
}

// =======================================================================================
// Fallback path (verified R5 kernel) — used when ws_size is too small for the MFMA path.
// =======================================================================================
#define NOISE 100
#define EMB   50
#define CIN1  306
#define S1    52

template<int PH>
__device__ __forceinline__ void conv1_full(const float* __restrict__ xt1, float* __restrict__ xt2,
                                           const float* __restrict__ wbase,
                                           float sc, float mm, float bb, int co){
    constexpr int OY0 = PH ? 4 : 0;
    constexpr int NOY = PH ? 3 : 4;
    float acc[NOY*7];
    #pragma unroll
    for (int i = 0; i < NOY*7; i++) acc[i] = 0.f;
    #pragma unroll 1
    for (int ci = 0; ci < CIN1; ci++){
        float xr[49];
        #pragma unroll
        for (int r = 0; r < 12; r++) *(float4*)&xr[4*r] = *(const float4*)&xt1[ci*S1 + 4*r];
        xr[48] = xt1[ci*S1 + 48];
        const float* wci = wbase + ci*256;
        #pragma unroll
        for (int ky = 0; ky < 5; ky++)
            #pragma unroll
            for (int kx = 0; kx < 5; kx++){
                float w = wci[(ky*5 + kx)*CIN1*256];
                #pragma unroll
                for (int oy = OY0; oy < OY0 + NOY; oy++){
                    int iy = oy + ky - 2;
                    if (iy < 0 || iy >= 7) continue;
                    #pragma unroll
                    for (int ox = 0; ox < 7; ox++){
                        int ix = ox + kx - 2;
                        if (ix < 0 || ix >= 7) continue;
                        acc[(oy - OY0)*7 + ox] += xr[iy*7 + ix] * w;
                    }
                }
            }
    }
    #pragma unroll
    for (int i = 0; i < NOY*7; i++){
        float y = (acc[i] - mm)*sc + bb;
        xt2[co*S1 + OY0*7 + i] = (y >= 0.f) ? y : ALPHA*y;
    }
}

template<int Q>
__device__ __forceinline__ void conv2_full(const float* __restrict__ xt2, float* __restrict__ xt3,
                                           const float* __restrict__ wbase,
                                           float sc, float mm, float bb, int co){
    float acc[49];
    #pragma unroll
    for (int i = 0; i < 49; i++) acc[i] = 0.f;
    #pragma unroll 1
    for (int ci = 0; ci < 256; ci++){
        float xr[49];
        #pragma unroll
        for (int r = 0; r < 12; r++) *(float4*)&xr[4*r] = *(const float4*)&xt2[ci*S1 + 4*r];
        xr[48] = xt2[ci*S1 + 48];
        const float* wci = wbase + ci*128;
        #pragma unroll
        for (int ky = 0; ky < 5; ky++)
            #pragma unroll
            for (int kx = 0; kx < 5; kx++){
                float w = wci[(ky*5 + kx)*256*128];
                #pragma unroll
                for (int ii = 0; ii < 49; ii++){
                    int p2 = Q*49 + ii;
                    int i = p2 / 14, j = p2 % 14;
                    int t = i + ky - 3, s = j + kx - 3;
                    if (t < 0 || (t & 1) || t >= 14) continue;
                    if (s < 0 || (s & 1) || s >= 14) continue;
                    acc[ii] += xr[(t >> 1)*7 + (s >> 1)] * w;
                }
            }
    }
    #pragma unroll
    for (int ii = 0; ii < 49; ii++){
        int p2 = Q*49 + ii;
        float y = (acc[ii] - mm)*sc + bb;
        xt3[p2*132 + co] = (y >= 0.f) ? y : ALPHA*y;
    }
}

__global__ __launch_bounds__(512, 2)
void fused_k(const float* __restrict__ noise, const int* __restrict__ labels,
             const float* __restrict__ emb,   const float* __restrict__ Wd,
             const float* __restrict__ g1,    const float* __restrict__ b1,
             const float* __restrict__ m1,    const float* __restrict__ v1,
             const float* __restrict__ K1,
             const float* __restrict__ G1, const float* __restrict__ B1,
             const float* __restrict__ M1, const float* __restrict__ V1,
             const float* __restrict__ K2,
             const float* __restrict__ G2, const float* __restrict__ B2,
             const float* __restrict__ M2, const float* __restrict__ V2,
             const float* __restrict__ K3,
             const int* __restrict__ order,
             float* __restrict__ out){
    __shared__ __align__(16) unsigned char smem[53248 + 103488];
    __shared__ float xin[152];
    float* xt2 = (float*)smem;
    float* wk  = (float*)smem;
    float* xt1 = (float*)(smem + 53248);
    float* xt3 = (float*)(smem + 53248);

    const int tid = threadIdx.x;
    const int idx = ((blockIdx.x & 7) << 6) | (blockIdx.x >> 3);
    const int b = order[idx];
    const int c = labels[b];

    if (tid < 150)
        xin[tid] = (tid < NOISE) ? noise[b*NOISE + tid] : emb[c*EMB + (tid - NOISE)];
    __syncthreads();
    {
        const int co = tid & 255;
        const int p0 = (tid >> 8) * 24;
        float acc[25];
        #pragma unroll
        for (int i = 0; i < 25; i++) acc[i] = 0.f;
        #pragma unroll 1
        for (int k = 0; k < 150; k++){
            float x = xin[k];
            const float* wr = Wd + k*12544 + p0*256 + co;
            #pragma unroll
            for (int i = 0; i < 25; i++) acc[i] += x * wr[i*256];
        }
        #pragma unroll
        for (int i = 0; i < 25; i++){
            int j = (p0 + i)*256 + co;
            float sc = g1[j] * rsqrtf(v1[j] + BNEPS);
            float y = (acc[i] - m1[j])*sc + b1[j];
            y = (y >= 0.f) ? y : ALPHA*y;
            xt1[co*S1 + p0 + i] = y;
        }
        if (tid < EMB){
            float v = xin[NOISE + tid];
            #pragma unroll
            for (int p = 0; p < 49; p++) xt1[(256 + tid)*S1 + p] = v;
        }
    }
    __syncthreads();
    {
        const int co = tid & 255;
        const int ph = tid >> 8;
        const float* wbase = K1 + (size_t)c*25*CIN1*256 + co;
        float sc = G1[c*256 + co] * rsqrtf(V1[c*256 + co] + BNEPS);
        float mm = M1[c*256 + co], bb = B1[c*256 + co];
        if (ph == 0) conv1_full<0>(xt1, xt2, wbase, sc, mm, bb, co);
        else         conv1_full<1>(xt1, xt2, wbase, sc, mm, bb, co);
    }
    __syncthreads();
    {
        const int co = tid & 127;
        const int q  = tid >> 7;
        const float* wbase = K2 + (size_t)c*25*256*128 + co;
        float sc = G2[c*128 + co] * rsqrtf(V2[c*128 + co] + BNEPS);
        float mm = M2[c*128 + co], bb = B2[c*128 + co];
        switch (q){
            case 0: conv2_full<0>(xt2, xt3, wbase, sc, mm, bb, co); break;
            case 1: conv2_full<1>(xt2, xt3, wbase, sc, mm, bb, co); break;
            case 2: conv2_full<2>(xt2, xt3, wbase, sc, mm, bb, co); break;
            default:conv2_full<3>(xt2, xt3, wbase, sc, mm, bb, co); break;
        }
    }
    __syncthreads();
    for (int i = tid; i < 3200; i += 512) wk[i] = K3[c*3200 + i];
    __syncthreads();
    #pragma unroll 1
    for (int rep = 0; rep < 2; rep++){
        int p3 = tid + rep*512;
        if (p3 < 784){
            int i = p3 / 28, j = p3 - (p3/28)*28;
            float acc = 0.f;
            #pragma unroll
            for (int ky = 0; ky < 5; ky++){
                int t = i + ky - 3;
                if (t < 0 || (t & 1) || t >= 28) continue;
                int u = t >> 1;
                #pragma unroll
                for (int kx = 0; kx < 5; kx++){
                    int s = j + kx - 3;
                    if (s < 0 || (s & 1) || s >= 28) continue;
                    int v = s >> 1;
                    const float* xr = &xt3[(u*14 + v)*132];
                    const float* w = &wk[(ky*5 + kx)*128];
                    #pragma unroll
                    for (int cc = 0; cc < 32; cc++){
                        float4 xv = *(const float4*)&xr[4*cc];
                        float4 wv = *(const float4*)&w[4*cc];
                        acc += xv.x*wv.x + xv.y*wv.y + xv.z*wv.z + xv.w*wv.w;
                    }
                }
            }
            out[b*784 + p3] = tanhf(acc);
        }
    }
}

extern "C" void kernel_launch(void* const* d_in, const int* in_sizes, int n_in,
                              void* d_out, int out_size, void* d_ws, size_t ws_size,
                              hipStream_t stream){
    const float* noise = (const float*)d_in[0];
    const int*   labels= (const int*)  d_in[1];
    const float* emb   = (const float*)d_in[2];
    const float* Wd    = (const float*)d_in[3];
    const float* g1    = (const float*)d_in[4];
    const float* b1    = (const float*)d_in[5];
    const float* m1    = (const float*)d_in[6];
    const float* v1    = (const float*)d_in[7];
    const float* K1    = (const float*)d_in[8];
    const float* G1    = (const float*)d_in[9];
    const float* B1    = (const float*)d_in[10];
    const float* M1    = (const float*)d_in[11];
    const float* V1    = (const float*)d_in[12];
    const float* K2    = (const float*)d_in[13];
    const float* G2    = (const float*)d_in[14];
    const float* B2    = (const float*)d_in[15];
    const float* M2    = (const float*)d_in[16];
    const float* V2    = (const float*)d_in[17];
    const float* K3    = (const float*)d_in[18];
    float* outp = (float*)d_out;

    // ws layout (bytes):
    //   order  @ 0        (2 KB)
    //   w1h    @ 4096     N1*2 = 40,960,000
    //   w1l               40,960,000
    //   w2h               16,384,000
    //   w2l               16,384,000
    //   xgH               16,056,320
    //   xgL               16,056,320
    const size_t NEED = 4096 + 2*(size_t)N1*2 + 2*(size_t)N2*2 + 2*(size_t)512*49*320*2;
    int* order = (int*)d_ws;

    if (ws_size >= NEED){
        short* w1h = (short*)((char*)d_ws + 4096);
        short* w1l = w1h + N1;
        short* w2h = w1l + N1;
        short* w2l = w2h + N2;
        short* xgH = w2l + N2;
        short* xgL = xgH + (size_t)512*49*320;
        sort_k <<<1, 512, 0, stream>>>(labels, order);
        prep_k <<<(N1 + N2)/256, 256, 0, stream>>>(K1, K2, w1h, w1l, w2h, w2l);
        dense_k<<<256, 256, 0, stream>>>(noise, labels, emb, Wd, g1, b1, m1, v1, xgH, xgL);
        main_k <<<256, 512, 0, stream>>>(labels, order, xgH, xgL, w1h, w1l, w2h, w2l,
                                         G1, B1, M1, V1, G2, B2, M2, V2, K3, outp);
    } else {
        // fallback: verified R5 path (needs only 2 KB ws)
        sort_k <<<1, 512, 0, stream>>>(labels, order);
        fused_k<<<512, 512, 0, stream>>>(noise, labels, emb, Wd, g1, b1, m1, v1,
                                         K1, G1, B1, M1, V1,
                                         K2, G2, B2, M2, V2, K3, order, outp);
    }
}

// Round 7
// 1049.496 us; speedup vs baseline: 2.7902x; 2.7902x over previous
//
#include <hip/hip_runtime.h>

#define ALPHA 0.3f
#define BNEPS 1e-3f

typedef __attribute__((ext_vector_type(8))) short bf16x8;
typedef __attribute__((ext_vector_type(4))) float f32x4;

__device__ __forceinline__ short f2bf(float x){
    unsigned u = __float_as_uint(x);
    unsigned r = (u + 0x7FFFu + ((u >> 16) & 1u)) >> 16;   // RNE
    return (short)r;
}
__device__ __forceinline__ float bf2f(short s){
    return __uint_as_float(((unsigned)(unsigned short)s) << 16);
}

// ---------------- routing: counting sort of samples by class ----------------
__global__ void sort_k(const int* __restrict__ labels, int* __restrict__ order){
    __shared__ int cnt[10], offs[10];
    int tid = threadIdx.x;
    if (tid < 10) cnt[tid] = 0;
    __syncthreads();
    int lab = labels[tid];
    atomicAdd(&cnt[lab], 1);
    __syncthreads();
    if (tid == 0){
        int s = 0;
        for (int c = 0; c < 10; c++){ offs[c] = s; s += cnt[c]; }
    }
    __syncthreads();
    int pos = atomicAdd(&offs[lab], 1);
    order[pos] = tid;
}

// ---------------- weight prep: fp32 -> bf16 hi/lo, B-fragment layout, fully coalesced ----
// W1T: [ct (250)][chunk=ci/8 (40)][co (256)][ci%8]   ci in [0,320), >=306 zero
// W2T: [ct][chunk=ci/8 (32)][co (128)][ci%8]
// thread = (ct, chunk, co): 8 lane-coalesced f32 reads, two 16B lane-coalesced writes.
#define N1 20480000   // 250*40*256*8
#define N2 8192000    // 250*32*128*8
#define T1 2560000    // 250*40*256
__global__ __launch_bounds__(256) void prep_k(const float* __restrict__ K1, const float* __restrict__ K2,
                       short* __restrict__ w1h, short* __restrict__ w1l,
                       short* __restrict__ w2h, short* __restrict__ w2l){
    int t = blockIdx.x * 256 + threadIdx.x;
    if (t < T1){
        int co = t & 255;
        int ch = (t >> 8) % 40;
        int ct = (t >> 8) / 40;
        bf16x8 h, l;
        #pragma unroll
        for (int j = 0; j < 8; j++){
            int ci = ch*8 + j;
            float w = (ci < 306) ? K1[((size_t)ct*306 + ci)*256 + co] : 0.f;
            short hh = f2bf(w);
            h[j] = hh;
            l[j] = f2bf(w - bf2f(hh));
        }
        size_t dst = (size_t)t * 8;
        *(bf16x8*)&w1h[dst] = h;
        *(bf16x8*)&w1l[dst] = l;
    } else {
        int tt = t - T1;
        int co = tt & 127;
        int ch = (tt >> 7) & 31;
        int ct = tt >> 12;
        bf16x8 h, l;
        #pragma unroll
        for (int j = 0; j < 8; j++){
            int ci = ch*8 + j;
            float w = K2[((size_t)ct*256 + ci)*128 + co];
            short hh = f2bf(w);
            h[j] = hh;
            l[j] = f2bf(w - bf2f(hh));
        }
        size_t dst = (size_t)tt * 8;
        *(bf16x8*)&w2h[dst] = h;
        *(bf16x8*)&w2l[dst] = l;
    }
}

// ---------------- dense 150->12544 + BN1 + LReLU -> xg hi/lo bf16 in ws ----------------
// xg[b][q 49][ci 320]; cols 256..305 = label emb; 306..319 = 0
// block = (q, 16-sample tile); Wd row read once per block (16-way reuse).
__global__ __launch_bounds__(256)
void dense_k(const float* __restrict__ noise, const int* __restrict__ labels,
             const float* __restrict__ emb,   const float* __restrict__ Wd,
             const float* __restrict__ g1, const float* __restrict__ b1,
             const float* __restrict__ m1, const float* __restrict__ v1,
             short* __restrict__ xgH, short* __restrict__ xgL){
    __shared__ float xs[16][152];
    const int tid = threadIdx.x;
    const int q  = blockIdx.x % 49;
    const int st = blockIdx.x / 49;
    for (int i = tid; i < 16*150; i += 256){
        int ss = i / 150, k = i % 150;
        int b = st*16 + ss;
        xs[ss][k] = (k < 100) ? noise[b*100 + k] : emb[labels[b]*50 + (k-100)];
    }
    __syncthreads();
    const int co = tid;
    const int j = q*256 + co;
    float acc[16];
    #pragma unroll
    for (int ss = 0; ss < 16; ss++) acc[ss] = 0.f;
    #pragma unroll 2
    for (int k = 0; k < 150; k++){
        float w = Wd[k*12544 + j];
        #pragma unroll
        for (int ss = 0; ss < 16; ss++)
            acc[ss] += xs[ss][k] * w;
    }
    float sc = g1[j] * rsqrtf(v1[j] + BNEPS);
    float mm = m1[j], bb = b1[j];
    #pragma unroll
    for (int ss = 0; ss < 16; ss++){
        float y = (acc[ss] - mm)*sc + bb;
        y = (y >= 0.f) ? y : ALPHA*y;
        short h = f2bf(y), l = f2bf(y - bf2f(h));
        size_t o = ((size_t)(st*16 + ss)*49 + q)*320 + co;
        xgH[o] = h; xgL[o] = l;
    }
    // cols 256..319: label emb (50) then zeros (14); thread = (ss, 4-col group)
    {
        int ss = tid >> 4, cg = tid & 15;
        #pragma unroll
        for (int cj = 0; cj < 4; cj++){
            int col = 256 + cg*4 + cj;
            float v = (col < 306) ? xs[ss][100 + col - 256] : 0.f;
            short h = f2bf(v), l = f2bf(v - bf2f(h));
            size_t o = ((size_t)(st*16 + ss)*49 + q)*320 + col;
            xgH[o] = h; xgL[o] = l;
        }
    }
}

// ---------------- main: conv1 + conv2 (MFMA hi/lo) + conv3 (VALU), 2 samples/block ----------------
// 1024 threads = 16 waves -> 4 waves/SIMD at 1 block/CU (latency hiding).
__global__ __launch_bounds__(1024, 1)
void main_k(const int* __restrict__ labels, const int* __restrict__ order,
            const short* __restrict__ xgH, const short* __restrict__ xgL,
            const short* __restrict__ w1h, const short* __restrict__ w1l,
            const short* __restrict__ w2h, const short* __restrict__ w2l,
            const float* __restrict__ G1, const float* __restrict__ B1,
            const float* __restrict__ M1, const float* __restrict__ V1,
            const float* __restrict__ G2, const float* __restrict__ B2,
            const float* __restrict__ M2, const float* __restrict__ V2,
            const float* __restrict__ K3, float* __restrict__ out){
    // smem overlay:
    //  conv1-in : xa1[s][h] = smem + (s*2+h)*16400 shorts, rows 50 x stride 328 (row 49 = zeros)
    //  conv2-in : xa2[s][h] = smem + (s*2+h)*13200 shorts, rows 50 x stride 264
    //  conv3    : h2f (196*132 f32) + wk3 (3200 f32) over same bytes
    __shared__ __align__(16) short smem[65600];          // 131,200 B
    __shared__ int binfo[4];                             // b0,b1,c0,c1
    const int tid = threadIdx.x;
    const int idx = ((blockIdx.x & 7) << 5) | (blockIdx.x >> 3);   // XCD swizzle, 256 blocks
    if (tid < 2){
        int b = order[2*idx + tid];
        binfo[tid] = b;
        binfo[2 + tid] = labels[b];
    }
    {   // zero LDS (padding rows rely on this)
        uint4 z; z.x = z.y = z.z = z.w = 0;
        uint4* p = (uint4*)smem;
        for (int i = tid; i < 8200; i += 1024) p[i] = z;
    }
    __syncthreads();
    // copy xcat rows (s,h,q): 196 rows x 40 uint4
    for (int i = tid; i < 7840; i += 1024){
        int t = i % 40, w = i / 40;
        int q = w % 49, sh = w / 49;
        int s = sh >> 1, h = sh & 1;
        const short* src = (h ? xgL : xgH) + ((size_t)binfo[s]*49 + q)*320;
        *(uint4*)&smem[sh*16400 + q*328 + t*8] = *(const uint4*)&src[t*8];
    }
    __syncthreads();

    const int lane = tid & 63, wid = tid >> 6;
    const int m15 = lane & 15, quad = lane >> 4;

    // ================= conv1: 7x7x306 -> 7x7x256 (s=1, pads 2,2) =================
    {
        const int s = wid & 1, nq = wid >> 1;          // wave = (sample, 32-col strip)
        const int c = binfo[2 + s];
        const short* xh = smem + (s*2 + 0)*16400;
        const short* xl = smem + (s*2 + 1)*16400;
        f32x4 acc[4][2];
        #pragma unroll
        for (int a = 0; a < 4; a++)
            #pragma unroll
            for (int b = 0; b < 2; b++){ acc[a][b][0]=0.f; acc[a][b][1]=0.f; acc[a][b][2]=0.f; acc[a][b][3]=0.f; }

        #pragma unroll 1
        for (int tap = 0; tap < 25; tap++){
            int ky = tap / 5, kx = tap % 5;
            int aoff[4];
            #pragma unroll
            for (int mi = 0; mi < 4; mi++){
                int p = mi*16 + m15;
                int py = p / 7, px = p % 7;
                int iy = py + ky - 2, ix = px + kx - 2;
                bool ok = (p < 49) & (iy >= 0) & (iy < 7) & (ix >= 0) & (ix < 7);
                int q = ok ? iy*7 + ix : 49;           // row 49 = zeros
                aoff[mi] = q*328 + quad*8;
            }
            const short *bh[2], *bl[2];
            size_t tapbase = ((size_t)(c*25 + tap))*40*256*8;
            #pragma unroll
            for (int ni = 0; ni < 2; ni++){
                int co = nq*32 + ni*16 + m15;
                size_t off = tapbase + ((size_t)quad*256 + co)*8;
                bh[ni] = w1h + off; bl[ni] = w1l + off;
            }
            #pragma unroll
            for (int ks = 0; ks < 10; ks++){
                bf16x8 Ah[4], Al[4], Bh[2], Bl[2];
                #pragma unroll
                for (int mi = 0; mi < 4; mi++){
                    Ah[mi] = *(const bf16x8*)&xh[aoff[mi] + ks*32];
                    Al[mi] = *(const bf16x8*)&xl[aoff[mi] + ks*32];
                }
                #pragma unroll
                for (int ni = 0; ni < 2; ni++){
                    Bh[ni] = *(const bf16x8*)&bh[ni][ks*8192];
                    Bl[ni] = *(const bf16x8*)&bl[ni][ks*8192];
                }
                #pragma unroll
                for (int mi = 0; mi < 4; mi++)
                    #pragma unroll
                    for (int ni = 0; ni < 2; ni++){
                        acc[mi][ni] = __builtin_amdgcn_mfma_f32_16x16x32_bf16(Ah[mi], Bh[ni], acc[mi][ni], 0, 0, 0);
                        acc[mi][ni] = __builtin_amdgcn_mfma_f32_16x16x32_bf16(Ah[mi], Bl[ni], acc[mi][ni], 0, 0, 0);
                        acc[mi][ni] = __builtin_amdgcn_mfma_f32_16x16x32_bf16(Al[mi], Bh[ni], acc[mi][ni], 0, 0, 0);
                    }
            }
        }
        __syncthreads();   // all conv1 LDS reads complete
        // epilogue: BN + LReLU -> xa2 (hi/lo), + zero row 49
        float sc[2], mm[2], bb[2];
        #pragma unroll
        for (int ni = 0; ni < 2; ni++){
            int co = nq*32 + ni*16 + m15;
            sc[ni] = G1[c*256 + co] * rsqrtf(V1[c*256 + co] + BNEPS);
            mm[ni] = M1[c*256 + co];
            bb[ni] = B1[c*256 + co];
        }
        short* yh = smem + (s*2 + 0)*13200;
        short* yl = smem + (s*2 + 1)*13200;
        yh[49*264 + nq*32 + (lane & 31)] = 0;
        yl[49*264 + nq*32 + (lane & 31)] = 0;
        #pragma unroll
        for (int mi = 0; mi < 4; mi++)
            #pragma unroll
            for (int r = 0; r < 4; r++){
                int p = mi*16 + quad*4 + r;
                if (p < 49){
                    #pragma unroll
                    for (int ni = 0; ni < 2; ni++){
                        float y = (acc[mi][ni][r] - mm[ni])*sc[ni] + bb[ni];
                        y = (y >= 0.f) ? y : ALPHA*y;
                        short h = f2bf(y), l = f2bf(y - bf2f(h));
                        int o = p*264 + nq*32 + ni*16 + m15;
                        yh[o] = h; yl[o] = l;
                    }
                }
            }
    }
    __syncthreads();

    // ================= conv2: 7x7x256 -> 14x14x128 (s=2, pads 3,2), parity split =================
    {
        const int s = wid & 1, par = (wid >> 1) & 3, nh = wid >> 3;  // wave = (sample, parity, col-half)
        const int pi = par >> 1, pj = par & 1;
        const int c = binfo[2 + s];
        const short* xh = smem + (s*2 + 0)*13200;
        const short* xl = smem + (s*2 + 1)*13200;
        f32x4 acc[4][4];                            // [mi][ni], 64 cols
        #pragma unroll
        for (int a = 0; a < 4; a++)
            #pragma unroll
            for (int b = 0; b < 4; b++){ acc[a][b][0]=0.f; acc[a][b][1]=0.f; acc[a][b][2]=0.f; acc[a][b][3]=0.f; }

        const int nky = pi ? 3 : 2, kyb = pi ? 0 : 1;
        const int nkx = pj ? 3 : 2, kxb = pj ? 0 : 1;
        #pragma unroll 1
        for (int ty = 0; ty < nky; ty++){
            int ky = kyb + 2*ty;
            int dy = (pi + ky - 3) / 2;
            #pragma unroll 1
            for (int tx = 0; tx < nkx; tx++){
                int kx = kxb + 2*tx;
                int dx = (pj + kx - 3) / 2;
                int tap = ky*5 + kx;
                int aoff[4];
                #pragma unroll
                for (int mi = 0; mi < 4; mi++){
                    int p = mi*16 + m15;
                    int oy = p / 7, ox = p % 7;
                    int u = oy + dy, v = ox + dx;
                    bool ok = (p < 49) & (u >= 0) & (u < 7) & (v >= 0) & (v < 7);
                    int q = ok ? u*7 + v : 49;
                    aoff[mi] = q*264 + quad*8;
                }
                const short *bh[4], *bl[4];
                size_t tapbase = ((size_t)(c*25 + tap))*32*128*8;
                #pragma unroll
                for (int ni = 0; ni < 4; ni++){
                    int co = nh*64 + ni*16 + m15;
                    size_t off = tapbase + ((size_t)quad*128 + co)*8;
                    bh[ni] = w2h + off; bl[ni] = w2l + off;
                }
                #pragma unroll
                for (int ks = 0; ks < 8; ks++){
                    bf16x8 Ah[4], Al[4];
                    #pragma unroll
                    for (int mi = 0; mi < 4; mi++){
                        Ah[mi] = *(const bf16x8*)&xh[aoff[mi] + ks*32];
                        Al[mi] = *(const bf16x8*)&xl[aoff[mi] + ks*32];
                    }
                    #pragma unroll
                    for (int ni = 0; ni < 4; ni++){
                        bf16x8 Bh = *(const bf16x8*)&bh[ni][ks*4096];
                        bf16x8 Bl = *(const bf16x8*)&bl[ni][ks*4096];
                        #pragma unroll
                        for (int mi = 0; mi < 4; mi++){
                            acc[mi][ni] = __builtin_amdgcn_mfma_f32_16x16x32_bf16(Ah[mi], Bh, acc[mi][ni], 0, 0, 0);
                            acc[mi][ni] = __builtin_amdgcn_mfma_f32_16x16x32_bf16(Ah[mi], Bl, acc[mi][ni], 0, 0, 0);
                            acc[mi][ni] = __builtin_amdgcn_mfma_f32_16x16x32_bf16(Al[mi], Bh, acc[mi][ni], 0, 0, 0);
                        }
                    }
                }
            }
        }
        __syncthreads();   // all conv2 LDS reads complete; smem free
        float sc[4], mm[4], bb[4];
        #pragma unroll
        for (int ni = 0; ni < 4; ni++){
            int co = nh*64 + ni*16 + m15;
            sc[ni] = G2[c*128 + co] * rsqrtf(V2[c*128 + co] + BNEPS);
            mm[ni] = M2[c*128 + co];
            bb[ni] = B2[c*128 + co];
        }
        float* h2f = (float*)smem;          // 196*132
        float* wk3 = (float*)smem + 25872;  // 3200
        #pragma unroll 1
        for (int sp = 0; sp < 2; sp++){
            if (s == sp){
                #pragma unroll
                for (int mi = 0; mi < 4; mi++)
                    #pragma unroll
                    for (int r = 0; r < 4; r++){
                        int p = mi*16 + quad*4 + r;
                        if (p < 49){
                            int oy = p / 7, ox = p % 7;
                            int q2 = (2*oy + pi)*14 + (2*ox + pj);
                            #pragma unroll
                            for (int ni = 0; ni < 4; ni++){
                                float y = (acc[mi][ni][r] - mm[ni])*sc[ni] + bb[ni];
                                y = (y >= 0.f) ? y : ALPHA*y;
                                h2f[q2*132 + nh*64 + ni*16 + m15] = y;
                            }
                        }
                    }
            }
            int cs = binfo[2 + sp];
            for (int i = tid; i < 3200; i += 1024) wk3[i] = K3[cs*3200 + i];
            __syncthreads();
            // conv3: 14x14x128 -> 28x28x1, s=2, pads (3,2), tanh
            int p3 = tid;
            if (p3 < 784){
                int oi = p3 / 28, oj = p3 % 28;
                float a3 = 0.f;
                #pragma unroll
                for (int ky = 0; ky < 5; ky++){
                    int t = oi + ky - 3;
                    if (t < 0 || (t & 1) || t >= 28) continue;
                    int u = t >> 1;
                    #pragma unroll
                    for (int kx = 0; kx < 5; kx++){
                        int ss2 = oj + kx - 3;
                        if (ss2 < 0 || (ss2 & 1) || ss2 >= 28) continue;
                        int v = ss2 >> 1;
                        const float* xr = &h2f[(u*14 + v)*132];
                        const float* w = &wk3[(ky*5 + kx)*128];
                        #pragma unroll
                        for (int cc = 0; cc < 32; cc++){
                            float4 xv = *(const float4*)&xr[4*cc];
                            float4 wv = *(const float4*)&w[4*cc];
                            a3 += xv.x*wv.x + xv.y*wv.y + xv.z*wv.z + xv.w*wv.w;
                        }
                    }
                }
                out[binfo[sp]*784 + p3] = tanhf(a3);
            }
            __syncthreads();   // before next sp overwrites h2f
        }
    }
}

// =======================================================================================
// Fallback path (verified R5 kernel) — used when ws_size is too small for the MFMA path.
// =======================================================================================
#define NOISE 100
#define EMB   50
#define CIN1  306
#define S1    52

template<int PH>
__device__ __forceinline__ void conv1_full(const float* __restrict__ xt1, float* __restrict__ xt2,
                                           const float* __restrict__ wbase,
                                           float sc, float mm, float bb, int co){
    constexpr int OY0 = PH ? 4 : 0;
    constexpr int NOY = PH ? 3 : 4;
    float acc[NOY*7];
    #pragma unroll
    for (int i = 0; i < NOY*7; i++) acc[i] = 0.f;
    #pragma unroll 1
    for (int ci = 0; ci < CIN1; ci++){
        float xr[49];
        #pragma unroll
        for (int r = 0; r < 12; r++) *(float4*)&xr[4*r] = *(const float4*)&xt1[ci*S1 + 4*r];
        xr[48] = xt1[ci*S1 + 48];
        const float* wci = wbase + ci*256;
        #pragma unroll
        for (int ky = 0; ky < 5; ky++)
            #pragma unroll
            for (int kx = 0; kx < 5; kx++){
                float w = wci[(ky*5 + kx)*CIN1*256];
                #pragma unroll
                for (int oy = OY0; oy < OY0 + NOY; oy++){
                    int iy = oy + ky - 2;
                    if (iy < 0 || iy >= 7) continue;
                    #pragma unroll
                    for (int ox = 0; ox < 7; ox++){
                        int ix = ox + kx - 2;
                        if (ix < 0 || ix >= 7) continue;
                        acc[(oy - OY0)*7 + ox] += xr[iy*7 + ix] * w;
                    }
                }
            }
    }
    #pragma unroll
    for (int i = 0; i < NOY*7; i++){
        float y = (acc[i] - mm)*sc + bb;
        xt2[co*S1 + OY0*7 + i] = (y >= 0.f) ? y : ALPHA*y;
    }
}

template<int Q>
__device__ __forceinline__ void conv2_full(const float* __restrict__ xt2, float* __restrict__ xt3,
                                           const float* __restrict__ wbase,
                                           float sc, float mm, float bb, int co){
    float acc[49];
    #pragma unroll
    for (int i = 0; i < 49; i++) acc[i] = 0.f;
    #pragma unroll 1
    for (int ci = 0; ci < 256; ci++){
        float xr[49];
        #pragma unroll
        for (int r = 0; r < 12; r++) *(float4*)&xr[4*r] = *(const float4*)&xt2[ci*S1 + 4*r];
        xr[48] = xt2[ci*S1 + 48];
        const float* wci = wbase + ci*128;
        #pragma unroll
        for (int ky = 0; ky < 5; ky++)
            #pragma unroll
            for (int kx = 0; kx < 5; kx++){
                float w = wci[(ky*5 + kx)*256*128];
                #pragma unroll
                for (int ii = 0; ii < 49; ii++){
                    int p2 = Q*49 + ii;
                    int i = p2 / 14, j = p2 % 14;
                    int t = i + ky - 3, s = j + kx - 3;
                    if (t < 0 || (t & 1) || t >= 14) continue;
                    if (s < 0 || (s & 1) || s >= 14) continue;
                    acc[ii] += xr[(t >> 1)*7 + (s >> 1)] * w;
                }
            }
    }
    #pragma unroll
    for (int ii = 0; ii < 49; ii++){
        int p2 = Q*49 + ii;
        float y = (acc[ii] - mm)*sc + bb;
        xt3[p2*132 + co] = (y >= 0.f) ? y : ALPHA*y;
    }
}

__global__ __launch_bounds__(512, 2)
void fused_k(const float* __restrict__ noise, const int* __restrict__ labels,
             const float* __restrict__ emb,   const float* __restrict__ Wd,
             const float* __restrict__ g1,    const float* __restrict__ b1,
             const float* __restrict__ m1,    const float* __restrict__ v1,
             const float* __restrict__ K1,
             const float* __restrict__ G1, const float* __restrict__ B1,
             const float* __restrict__ M1, const float* __restrict__ V1,
             const float* __restrict__ K2,
             const float* __restrict__ G2, const float* __restrict__ B2,
             const float* __restrict__ M2, const float* __restrict__ V2,
             const float* __restrict__ K3,
             const int* __restrict__ order,
             float* __restrict__ out){
    __shared__ __align__(16) unsigned char smem[53248 + 103488];
    __shared__ float xin[152];
    float* xt2 = (float*)smem;
    float* wk  = (float*)smem;
    float* xt1 = (float*)(smem + 53248);
    float* xt3 = (float*)(smem + 53248);

    const int tid = threadIdx.x;
    const int idx = ((blockIdx.x & 7) << 6) | (blockIdx.x >> 3);
    const int b = order[idx];
    const int c = labels[b];

    if (tid < 150)
        xin[tid] = (tid < NOISE) ? noise[b*NOISE + tid] : emb[c*EMB + (tid - NOISE)];
    __syncthreads();
    {
        const int co = tid & 255;
        const int p0 = (tid >> 8) * 24;
        float acc[25];
        #pragma unroll
        for (int i = 0; i < 25; i++) acc[i] = 0.f;
        #pragma unroll 1
        for (int k = 0; k < 150; k++){
            float x = xin[k];
            const float* wr = Wd + k*12544 + p0*256 + co;
            #pragma unroll
            for (int i = 0; i < 25; i++) acc[i] += x * wr[i*256];
        }
        #pragma unroll
        for (int i = 0; i < 25; i++){
            int j = (p0 + i)*256 + co;
            float sc = g1[j] * rsqrtf(v1[j] + BNEPS);
            float y = (acc[i] - m1[j])*sc + b1[j];
            y = (y >= 0.f) ? y : ALPHA*y;
            xt1[co*S1 + p0 + i] = y;
        }
        if (tid < EMB){
            float v = xin[NOISE + tid];
            #pragma unroll
            for (int p = 0; p < 49; p++) xt1[(256 + tid)*S1 + p] = v;
        }
    }
    __syncthreads();
    {
        const int co = tid & 255;
        const int ph = tid >> 8;
        const float* wbase = K1 + (size_t)c*25*CIN1*256 + co;
        float sc = G1[c*256 + co] * rsqrtf(V1[c*256 + co] + BNEPS);
        float mm = M1[c*256 + co], bb = B1[c*256 + co];
        if (ph == 0) conv1_full<0>(xt1, xt2, wbase, sc, mm, bb, co);
        else         conv1_full<1>(xt1, xt2, wbase, sc, mm, bb, co);
    }
    __syncthreads();
    {
        const int co = tid & 127;
        const int q  = tid >> 7;
        const float* wbase = K2 + (size_t)c*25*256*128 + co;
        float sc = G2[c*128 + co] * rsqrtf(V2[c*128 + co] + BNEPS);
        float mm = M2[c*128 + co], bb = B2[c*128 + co];
        switch (q){
            case 0: conv2_full<0>(xt2, xt3, wbase, sc, mm, bb, co); break;
            case 1: conv2_full<1>(xt2, xt3, wbase, sc, mm, bb, co); break;
            case 2: conv2_full<2>(xt2, xt3, wbase, sc, mm, bb, co); break;
            default:conv2_full<3>(xt2, xt3, wbase, sc, mm, bb, co); break;
        }
    }
    __syncthreads();
    for (int i = tid; i < 3200; i += 512) wk[i] = K3[c*3200 + i];
    __syncthreads();
    #pragma unroll 1
    for (int rep = 0; rep < 2; rep++){
        int p3 = tid + rep*512;
        if (p3 < 784){
            int i = p3 / 28, j = p3 - (p3/28)*28;
            float acc = 0.f;
            #pragma unroll
            for (int ky = 0; ky < 5; ky++){
                int t = i + ky - 3;
                if (t < 0 || (t & 1) || t >= 28) continue;
                int u = t >> 1;
                #pragma unroll
                for (int kx = 0; kx < 5; kx++){
                    int s = j + kx - 3;
                    if (s < 0 || (s & 1) || s >= 28) continue;
                    int v = s >> 1;
                    const float* xr = &xt3[(u*14 + v)*132];
                    const float* w = &wk[(ky*5 + kx)*128];
                    #pragma unroll
                    for (int cc = 0; cc < 32; cc++){
                        float4 xv = *(const float4*)&xr[4*cc];
                        float4 wv = *(const float4*)&w[4*cc];
                        acc += xv.x*wv.x + xv.y*wv.y + xv.z*wv.z + xv.w*wv.w;
                    }
                }
            }
            out[b*784 + p3] = tanhf(acc);
        }
    }
}

extern "C" void kernel_launch(void* const* d_in, const int* in_sizes, int n_in,
                              void* d_out, int out_size, void* d_ws, size_t ws_size,
                              hipStream_t stream){
    const float* noise = (const float*)d_in[0];
    const int*   labels= (const int*)  d_in[1];
    const float* emb   = (const float*)d_in[2];
    const float* Wd    = (const float*)d_in[3];
    const float* g1    = (const float*)d_in[4];
    const float* b1    = (const float*)d_in[5];
    const float* m1    = (const float*)d_in[6];
    const float* v1    = (const float*)d_in[7];
    const float* K1    = (const float*)d_in[8];
    const float* G1    = (const float*)d_in[9];
    const float* B1    = (const float*)d_in[10];
    const float* M1    = (const float*)d_in[11];
    const float* V1    = (const float*)d_in[12];
    const float* K2    = (const float*)d_in[13];
    const float* G2    = (const float*)d_in[14];
    const float* B2    = (const float*)d_in[15];
    const float* M2    = (const float*)d_in[16];
    const float* V2    = (const float*)d_in[17];
    const float* K3    = (const float*)d_in[18];
    float* outp = (float*)d_out;

    const size_t NEED = 4096 + 2*(size_t)N1*2 + 2*(size_t)N2*2 + 2*(size_t)512*49*320*2;
    int* order = (int*)d_ws;

    if (ws_size >= NEED){
        short* w1h = (short*)((char*)d_ws + 4096);
        short* w1l = w1h + N1;
        short* w2h = w1l + N1;
        short* w2l = w2h + N2;
        short* xgH = w2l + N2;
        short* xgL = xgH + (size_t)512*49*320;
        sort_k <<<1, 512, 0, stream>>>(labels, order);
        prep_k <<<(T1 + N2/8 + 255)/256, 256, 0, stream>>>(K1, K2, w1h, w1l, w2h, w2l);
        dense_k<<<49*32, 256, 0, stream>>>(noise, labels, emb, Wd, g1, b1, m1, v1, xgH, xgL);
        main_k <<<256, 1024, 0, stream>>>(labels, order, xgH, xgL, w1h, w1l, w2h, w2l,
                                          G1, B1, M1, V1, G2, B2, M2, V2, K3, outp);
    } else {
        // fallback: verified R5 path (needs only 2 KB ws)
        sort_k <<<1, 512, 0, stream>>>(labels, order);
        fused_k<<<512, 512, 0, stream>>>(noise, labels, emb, Wd, g1, b1, m1, v1,
                                         K1, G1, B1, M1, V1,
                                         K2, G2, B2, M2, V2, K3, order, outp);
    }
}